// Round 11
// baseline (1017.170 us; speedup 1.0000x reference)
//
#include <hip/hip_runtime.h>
#include <math.h>

// SparseDiffAttn: B=1, H=12, S=3840, D=128, BM=192 (QG=20), topk=1024.
// R11: R10 hit an L2-BW wall (every wave privately streamed the B operand:
// 4.15 GB L2/dispatch). Fix: share the streamed operand across the block's
// 4 waves via LDS (pure 16B copies of presplit data; fragment layout keeps
// ds_read_b128 conflict-free). Same MFMA products and accumulation order ->
// bit-identical rl/bs -> identical selection. sparse_attn gains a register
// double-buffer prefetch of the gathered K/V tile. Everything else unchanged.

#define HH 12
#define SS 3840
#define DD 128
#define QGn 20
#define TKn 1024
#define NROWS (HH * QGn)
#define HS (HH * SS)
#define NT 60            // 64-row tiles per head
#define TCH 3072         // 16B chunks per tile (64 rows x 128 dims x 3 comps)
#define SCALE_D 0.08838834764831845
#define SCALE_F 0.08838834764831845f

typedef short short8 __attribute__((ext_vector_type(8)));
typedef float f32x4 __attribute__((ext_vector_type(4)));

#define MFMA_B16(c, a, b) \
  c = __builtin_amdgcn_mfma_f32_16x16x32_bf16(a, b, c, 0, 0, 0)

__device__ __forceinline__ unsigned short bf_rne(float x) {
  unsigned u = __float_as_uint(x);
  u = (u + 0x7fffu + ((u >> 16) & 1u)) >> 16;
  return (unsigned short)u;
}
__device__ __forceinline__ float bf_f(unsigned short b) {
  return __uint_as_float(((unsigned)b) << 16);
}
__device__ __forceinline__ void split3(float f, unsigned short& a,
                                       unsigned short& b, unsigned short& c) {
  a = bf_rne(f);
  float r = f - bf_f(a);
  b = bf_rne(r);
  r = r - bf_f(b);
  c = bf_rne(r);
}
__device__ __forceinline__ void split2(float f, unsigned short& a,
                                       unsigned short& b) {
  a = bf_rne(f);
  float r = f - bf_f(a);
  b = bf_rne(r);
}
__device__ __forceinline__ short8 ldfrag(const unsigned short* base, int chunk) {
  return *(const short8*)&base[(size_t)chunk * 8];
}

// ---------------------------------------------------------------------------
// Kernel 0: presplit Q,K -> bf16 triples in fragment-chunk layout (R10).
// ---------------------------------------------------------------------------
__global__ __launch_bounds__(1024) void presplit_kernel(
    const float* __restrict__ q, const float* __restrict__ k,
    unsigned short* __restrict__ qsplit, unsigned short* __restrict__ ksplit) {
  const int t = threadIdx.x;
  const int lane = t & 63;
  const int u = t >> 6;
  const int kc = u & 3, kt = u >> 2;
  const int ln = lane & 15, quad = lane >> 4;
  const int c = blockIdx.x;
  const int h = blockIdx.y;
  const float* src = blockIdx.z ? k : q;
  unsigned short* dst = blockIdx.z ? ksplit : qsplit;

  const float* p =
      &src[(size_t)(h * SS + c * 64 + kt * 16 + ln) * DD + kc * 32 + quad * 8];
  float b8[8];
  *(float4*)&b8[0] = *(const float4*)&p[0];
  *(float4*)&b8[4] = *(const float4*)&p[4];
  unsigned short f0[8], f1[8], f2[8];
#pragma unroll
  for (int e = 0; e < 8; ++e) split3(b8[e], f0[e], f1[e], f2[e]);
  size_t base =
      ((size_t)(h * NT + c) * TCH + ((kt * 4 + kc) * 3) * 64 + lane) * 8;
  *(ushort4*)&dst[base + 0] = *(ushort4*)&f0[0];
  *(ushort4*)&dst[base + 4] = *(ushort4*)&f0[4];
  *(ushort4*)&dst[base + 512] = *(ushort4*)&f1[0];
  *(ushort4*)&dst[base + 516] = *(ushort4*)&f1[4];
  *(ushort4*)&dst[base + 1024] = *(ushort4*)&f2[0];
  *(ushort4*)&dst[base + 1028] = *(ushort4*)&f2[4];
}

// ---------------------------------------------------------------------------
// Kernel 1: partial softmax denominators. B-tile shared via LDS (4x traffic
// cut vs R10). grid (SS/128, HH, 4), block 256; wave w = 32 queries.
// ---------------------------------------------------------------------------
__global__ __launch_bounds__(256) void stats_mfma(
    const unsigned short* __restrict__ qsplit,
    const unsigned short* __restrict__ ksplit,
    double* __restrict__ lpart) {
  __shared__ unsigned short ktile[TCH * 8];   // 48 KB
  const int t = threadIdx.x;
  const int w = t >> 6;
  const int lane = t & 63;
  const int ln = lane & 15;
  const int quad = lane >> 4;
  const int h = blockIdx.y;
  const int nq = blockIdx.z;
  const int q0 = blockIdx.x * 128 + w * 32;
  const int tq = blockIdx.x * 2 + (w >> 1);
  const int ktA = (w & 1) * 2;

  short8 A[2][4][3];
  {
    const unsigned short* qb = &qsplit[(size_t)(h * NT + tq) * TCH * 8];
#pragma unroll
    for (int s = 0; s < 2; ++s)
#pragma unroll
      for (int kc = 0; kc < 4; ++kc)
#pragma unroll
        for (int cm = 0; cm < 3; ++cm)
          A[s][kc][cm] =
              ldfrag(qb, (((ktA + s) * 4 + kc) * 3 + cm) * 64 + lane);
  }

  double racc[2][4];
#pragma unroll
  for (int s = 0; s < 2; ++s)
#pragma unroll
    for (int r = 0; r < 4; ++r) racc[s][r] = 0.0;

  for (int c = nq * 15; c < nq * 15 + 15; ++c) {
    const unsigned short* kb = &ksplit[(size_t)(h * NT + c) * TCH * 8];
    __syncthreads();
#pragma unroll
    for (int j = 0; j < 12; ++j) {
      int chunk = j * 256 + t;
      *(uint4*)&ktile[chunk * 8] = *(const uint4*)&kb[(size_t)chunk * 8];
    }
    __syncthreads();

#pragma unroll
    for (int kt = 0; kt < 4; ++kt) {
      f32x4 C[2][3];
#pragma unroll
      for (int s = 0; s < 2; ++s)
#pragma unroll
        for (int m = 0; m < 3; ++m) C[s][m] = (f32x4){0.f, 0.f, 0.f, 0.f};
#pragma unroll
      for (int kc = 0; kc < 4; ++kc) {
        short8 B0 = *(const short8*)&ktile[(((kt * 4 + kc) * 3 + 0) * 64 + lane) * 8];
        short8 B1 = *(const short8*)&ktile[(((kt * 4 + kc) * 3 + 1) * 64 + lane) * 8];
        short8 B2 = *(const short8*)&ktile[(((kt * 4 + kc) * 3 + 2) * 64 + lane) * 8];
#pragma unroll
        for (int s = 0; s < 2; ++s) {
          MFMA_B16(C[s][0], A[s][kc][0], B0);
          MFMA_B16(C[s][1], A[s][kc][0], B1);
          MFMA_B16(C[s][1], A[s][kc][1], B0);
          MFMA_B16(C[s][0], A[s][kc][1], B1);
          MFMA_B16(C[s][2], A[s][kc][2], B0);
          MFMA_B16(C[s][2], A[s][kc][0], B2);
        }
      }
#pragma unroll
      for (int s = 0; s < 2; ++s)
#pragma unroll
        for (int r = 0; r < 4; ++r) {
          float sv = (C[s][0][r] + C[s][1][r]) + C[s][2][r];
          racc[s][r] += (double)__expf(sv * SCALE_F);
        }
    }
  }

#pragma unroll
  for (int s = 0; s < 2; ++s)
#pragma unroll
    for (int r = 0; r < 4; ++r) {
      double v = racc[s][r];
      v += __shfl_xor(v, 1);
      v += __shfl_xor(v, 2);
      v += __shfl_xor(v, 4);
      v += __shfl_xor(v, 8);
      if (ln == 0)
        lpart[(size_t)nq * HS + h * SS + q0 + s * 16 + quad * 4 + r] = v;
    }
}

// ---------------------------------------------------------------------------
// Kernel 2: bs colsums. A-stream shared via LDS; Bk persistent per wave.
// grid (SS/128, QGn, HH), block 256; wave w = 32 keys.
// ---------------------------------------------------------------------------
__global__ __launch_bounds__(256) void colsum_mfma(
    const unsigned short* __restrict__ qsplit,
    const unsigned short* __restrict__ ksplit,
    const double* __restrict__ lpart, double* __restrict__ bs) {
  __shared__ unsigned short qtile[TCH * 8];   // 48 KB
  __shared__ double rls[192];
  const int t = threadIdx.x;
  const int w = t >> 6;
  const int lane = t & 63;
  const int ln = lane & 15;
  const int quad = lane >> 4;
  const int h = blockIdx.z, g = blockIdx.y;
  const int k0 = blockIdx.x * 128 + w * 32;
  const int tk = blockIdx.x * 2 + (w >> 1);
  const int ktB = (w & 1) * 2;

  short8 Bk[2][4][3];
  {
    const unsigned short* kb = &ksplit[(size_t)(h * NT + tk) * TCH * 8];
#pragma unroll
    for (int s = 0; s < 2; ++s)
#pragma unroll
      for (int kc = 0; kc < 4; ++kc)
#pragma unroll
        for (int cm = 0; cm < 3; ++cm)
          Bk[s][kc][cm] =
              ldfrag(kb, (((ktB + s) * 4 + kc) * 3 + cm) * 64 + lane);
  }

  if (t < 192) {
    size_t qi = h * SS + g * 192 + t;
    rls[t] = 1.0 / (lpart[qi] + lpart[HS + qi] + lpart[2 * (size_t)HS + qi] +
                    lpart[3 * (size_t)HS + qi]);
  }

  double cacc[2] = {0.0, 0.0};

  for (int qc = 0; qc < 3; ++qc) {
    const unsigned short* qb = &qsplit[(size_t)(h * NT + g * 3 + qc) * TCH * 8];
    __syncthreads();
#pragma unroll
    for (int j = 0; j < 12; ++j) {
      int chunk = j * 256 + t;
      *(uint4*)&qtile[chunk * 8] = *(const uint4*)&qb[(size_t)chunk * 8];
    }
    __syncthreads();

#pragma unroll
    for (int qt = 0; qt < 4; ++qt) {
      f32x4 C[2][3];
#pragma unroll
      for (int s = 0; s < 2; ++s)
#pragma unroll
        for (int m = 0; m < 3; ++m) C[s][m] = (f32x4){0.f, 0.f, 0.f, 0.f};
#pragma unroll
      for (int kc = 0; kc < 4; ++kc) {
        short8 A0 = *(const short8*)&qtile[(((qt * 4 + kc) * 3 + 0) * 64 + lane) * 8];
        short8 A1 = *(const short8*)&qtile[(((qt * 4 + kc) * 3 + 1) * 64 + lane) * 8];
        short8 A2 = *(const short8*)&qtile[(((qt * 4 + kc) * 3 + 2) * 64 + lane) * 8];
#pragma unroll
        for (int s = 0; s < 2; ++s) {
          MFMA_B16(C[s][0], A0, Bk[s][kc][0]);
          MFMA_B16(C[s][1], A1, Bk[s][kc][0]);
          MFMA_B16(C[s][1], A0, Bk[s][kc][1]);
          MFMA_B16(C[s][0], A1, Bk[s][kc][1]);
          MFMA_B16(C[s][2], A2, Bk[s][kc][0]);
          MFMA_B16(C[s][2], A0, Bk[s][kc][2]);
        }
      }
#pragma unroll
      for (int s = 0; s < 2; ++s)
#pragma unroll
        for (int r = 0; r < 4; ++r) {
          float p = __expf(((C[s][0][r] + C[s][1][r]) + C[s][2][r]) * SCALE_F);
          cacc[s] += (double)p * rls[qc * 64 + qt * 16 + quad * 4 + r];
        }
    }
  }

#pragma unroll
  for (int s = 0; s < 2; ++s) {
    double v = cacc[s];
    v += __shfl_xor(v, 16);
    v += __shfl_xor(v, 32);
    if (quad == 0)
      bs[(size_t)(h * QGn + g) * SS + k0 + s * 16 + ln] = v;
  }
}

// ---------------------------------------------------------------------------
// Kernel 3: radix top-1024 + boundary capture (unchanged).
// ---------------------------------------------------------------------------
__global__ __launch_bounds__(256) void topk3_kernel(
    const double* __restrict__ bs, int* __restrict__ inds,
    double* __restrict__ bnd_val, int* __restrict__ bnd_idx) {
  __shared__ unsigned long long u[SS];
  __shared__ int hist[256];
  __shared__ int s_bin, s_r;
  __shared__ int c_gt, c_eq;
  __shared__ unsigned long long rv[256];
  __shared__ int ri[256];
  const int t = threadIdx.x;
  const int row = blockIdx.x;
  const double* vals = bs + (size_t)row * SS;

  for (int i = t; i < SS; i += 256)
    u[i] = (unsigned long long)__double_as_longlong(vals[i]);

  unsigned long long pref = 0ull;
  int r = TKn;
  for (int shift = 56; shift >= 0; shift -= 8) {
    hist[t] = 0;
    __syncthreads();
    unsigned long long himask =
        (shift == 56) ? 0ull : (0xFFFFFFFFFFFFFFFFull << (shift + 8));
    for (int i = t; i < SS; i += 256) {
      unsigned long long uv = u[i];
      if ((uv & himask) == (pref & himask))
        atomicAdd(&hist[(int)((uv >> shift) & 255)], 1);
    }
    __syncthreads();
    if (t == 0) {
      int cum = 0;
      for (int b = 255; b >= 0; --b) {
        int c = hist[b];
        if (cum + c >= r) { s_bin = b; s_r = r - cum; break; }
        cum += c;
      }
      c_gt = 0;
      c_eq = 0;
    }
    __syncthreads();
    pref |= ((unsigned long long)s_bin) << shift;
    r = s_r;
    __syncthreads();
  }
  const int G = TKn - r;
  int* out = inds + (size_t)row * TKn;
  unsigned long long mb = 0ull;
  int mbi = -1;
  for (int i = t; i < SS; i += 256) {
    unsigned long long uv = u[i];
    if (uv > pref) {
      int p = atomicAdd(&c_gt, 1);
      out[p] = i;
    } else if (uv == pref) {
      int e = atomicAdd(&c_eq, 1);
      if (e < r) out[G + e] = i;
      if (e == r - 1) bnd_idx[row * 2 + 0] = i;
    } else if (uv > mb) {
      mb = uv;
      mbi = i;
    }
  }
  rv[t] = mb;
  ri[t] = mbi;
  __syncthreads();
  for (int s2 = 128; s2 > 0; s2 >>= 1) {
    if (t < s2 && rv[t + s2] > rv[t]) {
      rv[t] = rv[t + s2];
      ri[t] = ri[t + s2];
    }
    __syncthreads();
  }
  if (t == 0) {
    bnd_val[row * 2 + 0] = __longlong_as_double((long long)pref);
    bnd_val[row * 2 + 1] = __longlong_as_double((long long)rv[0]);
    bnd_idx[row * 2 + 1] = ri[0];
  }
}

// ---------------------------------------------------------------------------
__global__ __launch_bounds__(256) void argmin_kernel(
    const double* __restrict__ bnd_val, const int* __restrict__ bnd_idx,
    int* __restrict__ rsel) {
  __shared__ double gmin[256];
  __shared__ int grow[256];
  const int t = threadIdx.x;
  double g = 1e300;
  int r = -1;
  if (t < NROWS) {
    g = bnd_val[t * 2 + 0] - bnd_val[t * 2 + 1];
    r = t;
  }
  gmin[t] = g;
  grow[t] = r;
  __syncthreads();
  for (int s2 = 128; s2 > 0; s2 >>= 1) {
    if (t < s2 && gmin[t + s2] < gmin[t]) {
      gmin[t] = gmin[t + s2];
      grow[t] = grow[t + s2];
    }
    __syncthreads();
  }
  if (t == 0) {
    int rr = grow[0];
    rsel[0] = rr;
    rsel[1] = bnd_idx[rr * 2 + 0];
    rsel[2] = bnd_idx[rr * 2 + 1];
  }
}

// ---------------------------------------------------------------------------
__global__ __launch_bounds__(256) void exact_rl_kernel(
    const float* __restrict__ q, const float* __restrict__ k,
    const int* __restrict__ rsel, double* __restrict__ rl_exact) {
  __shared__ double qd[DD];
  __shared__ double red[256];
  const int t = threadIdx.x;
  const int row = rsel[0];
  const int h = row / QGn, g = row % QGn;
  const float* qp = &q[(size_t)(h * SS + g * 192 + blockIdx.x) * DD];
  if (t < DD) qd[t] = (double)qp[t];
  __syncthreads();
  double l = 0.0;
  for (int kk = t; kk < SS; kk += 256) {
    const float* kp = &k[(size_t)(h * SS + kk) * DD];
    double s = 0.0;
#pragma unroll 4
    for (int d = 0; d < DD; d += 4) {
      float4 kv = *(const float4*)&kp[d];
      s += qd[d] * (double)kv.x + qd[d + 1] * (double)kv.y +
           qd[d + 2] * (double)kv.z + qd[d + 3] * (double)kv.w;
    }
    l += exp(s * SCALE_D);
  }
  red[t] = l;
  __syncthreads();
  for (int s2 = 128; s2 > 0; s2 >>= 1) {
    if (t < s2) red[t] += red[t + s2];
    __syncthreads();
  }
  if (t == 0) rl_exact[blockIdx.x] = 1.0 / red[0];
}

// ---------------------------------------------------------------------------
__global__ __launch_bounds__(256) void exact_pair_kernel(
    const float* __restrict__ q, const float* __restrict__ k,
    const int* __restrict__ rsel, const double* __restrict__ rl_exact,
    int* __restrict__ inds) {
  __shared__ double redX[256], redY[256];
  const int t = threadIdx.x;
  const int row = rsel[0], kept = rsel[1], drop = rsel[2];
  const int h = row / QGn, g = row % QGn;
  double px = 0.0, py = 0.0;
  if (t < 192) {
    const float* qp = &q[(size_t)(h * SS + g * 192 + t) * DD];
    const float* kx = &k[(size_t)(h * SS + kept) * DD];
    const float* ky = &k[(size_t)(h * SS + drop) * DD];
    double sx = 0.0, sy = 0.0;
#pragma unroll 4
    for (int d = 0; d < DD; ++d) {
      double qv = (double)qp[d];
      sx += qv * (double)kx[d];
      sy += qv * (double)ky[d];
    }
    double rv = rl_exact[t];
    px = exp(sx * SCALE_D) * rv;
    py = exp(sy * SCALE_D) * rv;
  }
  redX[t] = px;
  redY[t] = py;
  __syncthreads();
  for (int s2 = 128; s2 > 0; s2 >>= 1) {
    if (t < s2) { redX[t] += redX[t + s2]; redY[t] += redY[t + s2]; }
    __syncthreads();
  }
  if (t == 0)
    inds[(size_t)row * TKn + (TKn - 1)] = (redX[0] <= redY[0]) ? kept : drop;
}

// ---------------------------------------------------------------------------
// Kernel 4: MFMA sparse gathered attention + register double-buffer prefetch
// of the gathered K/V tile (global gather latency overlaps compute).
// grid (3, QGn, HH), block 256.
// ---------------------------------------------------------------------------
__global__ __launch_bounds__(256, 3) void sparse_attn_mfma(
    const float* __restrict__ q, const float* __restrict__ k,
    const float* __restrict__ v, const int* __restrict__ inds,
    float* __restrict__ out) {
  __shared__ unsigned short ksm[2][32][136];
  __shared__ unsigned short vsm[2][128][40];
  __shared__ unsigned short pbuf[4][2][16][40];
  const int t = threadIdx.x;
  const int w = t >> 6;
  const int lane = t & 63;
  const int ln = lane & 15;
  const int quad = lane >> 4;
  const int h = blockIdx.z, g = blockIdx.y;
  const int qbase = g * 192 + blockIdx.x * 64;
  const int* ip = &inds[(size_t)(h * QGn + g) * TKn];

  short8 A[4][2];
  {
    const float* qp = &q[(size_t)(h * SS + qbase + w * 16 + ln) * DD + quad * 8];
#pragma unroll
    for (int kc = 0; kc < 4; ++kc) {
      float b8[8];
      *(float4*)&b8[0] = *(const float4*)&qp[kc * 32];
      *(float4*)&b8[4] = *(const float4*)&qp[kc * 32 + 4];
      short8 f0, f1;
#pragma unroll
      for (int e = 0; e < 8; ++e) {
        unsigned short x0, x1;
        split2(b8[e], x0, x1);
        f0[e] = (short)x0; f1[e] = (short)x1;
      }
      A[kc][0] = f0; A[kc][1] = f1;
    }
  }

  f32x4 O[8];
#pragma unroll
  for (int dt = 0; dt < 8; ++dt) O[dt] = (f32x4){0.f, 0.f, 0.f, 0.f};
  float lacc[4] = {0.f, 0.f, 0.f, 0.f};

  const int kk = t >> 3;
  const int sub = t & 7;

  float4 pk[4], pv[4];   // prefetch buffers: one K row chunk + one V row chunk
  {
    int gk = ip[kk];
    const float* kp = &k[(size_t)(h * SS + gk) * DD + sub * 16];
    const float* vp = &v[(size_t)(h * SS + gk) * DD + sub * 16];
#pragma unroll
    for (int e4 = 0; e4 < 4; ++e4) {
      pk[e4] = *(const float4*)&kp[e4 * 4];
      pv[e4] = *(const float4*)&vp[e4 * 4];
    }
  }

  for (int kt = 0; kt < TKn; kt += 32) {
    __syncthreads();
#pragma unroll
    for (int e4 = 0; e4 < 4; ++e4) {
      float4 kv = pk[e4];
      ushort4 k0, k1;
      split2(kv.x, k0.x, k1.x);
      split2(kv.y, k0.y, k1.y);
      split2(kv.z, k0.z, k1.z);
      split2(kv.w, k0.w, k1.w);
      *(ushort4*)&ksm[0][kk][sub * 16 + e4 * 4] = k0;
      *(ushort4*)&ksm[1][kk][sub * 16 + e4 * 4] = k1;
      float4 vv = pv[e4];
      ushort4 v0, v1;
      split2(vv.x, v0.x, v1.x);
      split2(vv.y, v0.y, v1.y);
      split2(vv.z, v0.z, v1.z);
      split2(vv.w, v0.w, v1.w);
      int d0 = sub * 16 + e4 * 4;
      vsm[0][d0 + 0][kk] = v0.x; vsm[1][d0 + 0][kk] = v1.x;
      vsm[0][d0 + 1][kk] = v0.y; vsm[1][d0 + 1][kk] = v1.y;
      vsm[0][d0 + 2][kk] = v0.z; vsm[1][d0 + 2][kk] = v1.z;
      vsm[0][d0 + 3][kk] = v0.w; vsm[1][d0 + 3][kk] = v1.w;
    }
    __syncthreads();

    if (kt + 32 < TKn) {   // prefetch next tile; overlaps compute below
      int gk = ip[kt + 32 + kk];
      const float* kp = &k[(size_t)(h * SS + gk) * DD + sub * 16];
      const float* vp = &v[(size_t)(h * SS + gk) * DD + sub * 16];
#pragma unroll
      for (int e4 = 0; e4 < 4; ++e4) {
        pk[e4] = *(const float4*)&kp[e4 * 4];
        pv[e4] = *(const float4*)&vp[e4 * 4];
      }
    }

#pragma unroll
    for (int s = 0; s < 2; ++s) {
      f32x4 C0 = {0.f, 0.f, 0.f, 0.f};
      f32x4 C1 = C0;
#pragma unroll
      for (int kc = 0; kc < 4; ++kc) {
        short8 B0 = *(const short8*)&ksm[0][s * 16 + ln][kc * 32 + quad * 8];
        short8 B1 = *(const short8*)&ksm[1][s * 16 + ln][kc * 32 + quad * 8];
        MFMA_B16(C0, A[kc][0], B0);
        MFMA_B16(C1, A[kc][1], B0);
        MFMA_B16(C1, A[kc][0], B1);
      }
#pragma unroll
      for (int r = 0; r < 4; ++r) {
        float pvx = __expf((C0[r] + C1[r]) * SCALE_F);
        lacc[r] += pvx;
        unsigned short p0, p1;
        split2(pvx, p0, p1);
        pbuf[w][0][quad * 4 + r][s * 16 + ln] = p0;
        pbuf[w][1][quad * 4 + r][s * 16 + ln] = p1;
      }
    }
    short8 P0 = *(const short8*)&pbuf[w][0][ln][quad * 8];
    short8 P1 = *(const short8*)&pbuf[w][1][ln][quad * 8];
#pragma unroll
    for (int dt = 0; dt < 8; ++dt) {
      short8 V0 = *(const short8*)&vsm[0][dt * 16 + ln][quad * 8];
      short8 V1 = *(const short8*)&vsm[1][dt * 16 + ln][quad * 8];
      MFMA_B16(O[dt], P0, V0);
      MFMA_B16(O[dt], P1, V0);
      MFMA_B16(O[dt], P0, V1);
    }
  }

#pragma unroll
  for (int r = 0; r < 4; ++r) {
    float l = lacc[r];
    l += __shfl_xor(l, 1);
    l += __shfl_xor(l, 2);
    l += __shfl_xor(l, 4);
    l += __shfl_xor(l, 8);
    float rl = 1.f / l;
    float* op = &out[(size_t)(h * SS + qbase + w * 16 + quad * 4 + r) * DD];
#pragma unroll
    for (int dt = 0; dt < 8; ++dt) op[dt * 16 + ln] = O[dt][r] * rl;
  }
}

// ---------------------------------------------------------------------------
extern "C" void kernel_launch(void* const* d_in, const int* in_sizes, int n_in,
                              void* d_out, int out_size, void* d_ws, size_t ws_size,
                              hipStream_t stream) {
  const float* q = (const float*)d_in[0];
  const float* k = (const float*)d_in[1];
  const float* v = (const float*)d_in[2];
  float* out = (float*)d_out;

  const size_t SPLIT_ELEMS = (size_t)HH * NT * TCH * 8;
  unsigned short* qsplit = (unsigned short*)d_ws;
  unsigned short* ksplit = qsplit + SPLIT_ELEMS;
  double* lpart = (double*)(ksplit + SPLIT_ELEMS);        // [4*HS]
  double* bs = lpart + 4 * (size_t)HS;                    // [HH*QGn*SS]
  int* inds = (int*)(bs + (size_t)HH * QGn * SS);         // [NROWS*TKn]
  double* bnd_val = (double*)(inds + (size_t)NROWS * TKn);// [NROWS*2]
  int* bnd_idx = (int*)(bnd_val + (size_t)NROWS * 2);     // [NROWS*2]
  int* rsel = bnd_idx + NROWS * 2;                        // [4]
  double* rl_exact = (double*)(rsel + 4);                 // [192]

  presplit_kernel<<<dim3(NT, HH, 2), 1024, 0, stream>>>(q, k, qsplit, ksplit);
  stats_mfma<<<dim3(SS / 128, HH, 4), 256, 0, stream>>>(qsplit, ksplit, lpart);
  colsum_mfma<<<dim3(SS / 128, QGn, HH), 256, 0, stream>>>(qsplit, ksplit, lpart, bs);
  topk3_kernel<<<dim3(NROWS), 256, 0, stream>>>(bs, inds, bnd_val, bnd_idx);
  argmin_kernel<<<dim3(1), 256, 0, stream>>>(bnd_val, bnd_idx, rsel);
  exact_rl_kernel<<<dim3(192), 256, 0, stream>>>(q, k, rsel, rl_exact);
  exact_pair_kernel<<<dim3(1), 256, 0, stream>>>(q, k, rsel, rl_exact, inds);
  sparse_attn_mfma<<<dim3(3, QGn, HH), 256, 0, stream>>>(q, k, v, inds, out);
}